// Round 1
// 2633.589 us; speedup vs baseline: 1.1467x; 1.1467x over previous
//
#include <hip/hip_runtime.h>
#include <cstdint>
#include <cstddef>

#define S_ 2048
#define H_ 2048
#define NH_ 16
#define HD_ 128
#define L_ 2
#define V_ 32000
#define ROT_ 32

typedef __bf16 bf16x8 __attribute__((ext_vector_type(8)));
typedef float f32x4 __attribute__((ext_vector_type(4)));

__device__ __forceinline__ unsigned short f2bf(float f) {
    unsigned u = __builtin_bit_cast(unsigned, f);
    unsigned r = u + 0x7fffu + ((u >> 16) & 1u);
    return (unsigned short)(r >> 16);
}
__device__ __forceinline__ float bf2f(unsigned short h) {
    return __builtin_bit_cast(float, (unsigned)h << 16);
}
__device__ __forceinline__ float gelu_f(float x) {
    float t = 0.79788456f * x * (1.0f + 0.044715f * x * x);
    return x * 0.5f * (1.0f + tanhf(t));
}

// ---------------- embedding gather ----------------
__global__ __launch_bounds__(256) void k_embed(const int* __restrict__ tok,
                                               const float* __restrict__ emb,
                                               float* __restrict__ h) {
    int s = blockIdx.x;
    int t = tok[s];
    const float4* src = (const float4*)(emb + (size_t)t * H_);
    float4* dst = (float4*)(h + (size_t)s * H_);
    for (int i = threadIdx.x; i < H_ / 4; i += 256) dst[i] = src[i];
}

// ---------------- fp32 -> bf16 weight conversion (streaming) ----------------
__global__ __launch_bounds__(256) void k_cvt(const float* __restrict__ src,
                                             unsigned short* __restrict__ dst, int n4) {
    int stride = gridDim.x * 256;
    for (int i = blockIdx.x * 256 + threadIdx.x; i < n4; i += stride) {
        float4 v = ((const float4*)src)[i];
        uint2 p;
        p.x = f2bf(v.x) | ((unsigned)f2bf(v.y) << 16);
        p.y = f2bf(v.z) | ((unsigned)f2bf(v.w) << 16);
        ((uint2*)dst)[i] = p;
    }
}

// ---------------- layernorm (fp32 in, bf16 out) ----------------
__global__ __launch_bounds__(256) void k_ln(const float* __restrict__ x,
                                            const float* __restrict__ g,
                                            const float* __restrict__ b,
                                            unsigned short* __restrict__ out) {
    int s = blockIdx.x;
    int tid = threadIdx.x;
    const float4* xr = (const float4*)(x + (size_t)s * H_);
    float4 v0 = xr[tid], v1 = xr[tid + 256];
    float s1 = v0.x + v0.y + v0.z + v0.w + v1.x + v1.y + v1.z + v1.w;
    float s2 = v0.x * v0.x + v0.y * v0.y + v0.z * v0.z + v0.w * v0.w +
               v1.x * v1.x + v1.y * v1.y + v1.z * v1.z + v1.w * v1.w;
    #pragma unroll
    for (int off = 32; off > 0; off >>= 1) {
        s1 += __shfl_down(s1, off);
        s2 += __shfl_down(s2, off);
    }
    __shared__ float red[2][4];
    int wave = tid >> 6, lane = tid & 63;
    if (lane == 0) { red[0][wave] = s1; red[1][wave] = s2; }
    __syncthreads();
    s1 = red[0][0] + red[0][1] + red[0][2] + red[0][3];
    s2 = red[1][0] + red[1][1] + red[1][2] + red[1][3];
    float mean = s1 * (1.0f / H_);
    float var = s2 * (1.0f / H_) - mean * mean;
    float rstd = rsqrtf(var + 1e-5f);
    unsigned short* orow = out + (size_t)s * H_;
    int e0 = tid * 4, e1 = (tid + 256) * 4;
    unsigned short h0 = f2bf((v0.x - mean) * rstd * g[e0 + 0] + b[e0 + 0]);
    unsigned short h1 = f2bf((v0.y - mean) * rstd * g[e0 + 1] + b[e0 + 1]);
    unsigned short h2 = f2bf((v0.z - mean) * rstd * g[e0 + 2] + b[e0 + 2]);
    unsigned short h3 = f2bf((v0.w - mean) * rstd * g[e0 + 3] + b[e0 + 3]);
    uint2 p0; p0.x = h0 | ((unsigned)h1 << 16); p0.y = h2 | ((unsigned)h3 << 16);
    ((uint2*)orow)[tid] = p0;
    h0 = f2bf((v1.x - mean) * rstd * g[e1 + 0] + b[e1 + 0]);
    h1 = f2bf((v1.y - mean) * rstd * g[e1 + 1] + b[e1 + 1]);
    h2 = f2bf((v1.z - mean) * rstd * g[e1 + 2] + b[e1 + 2]);
    h3 = f2bf((v1.w - mean) * rstd * g[e1 + 3] + b[e1 + 3]);
    uint2 p1; p1.x = h0 | ((unsigned)h1 << 16); p1.y = h2 | ((unsigned)h3 << 16);
    ((uint2*)orow)[tid + 256] = p1;
}

// ---------------- GEMM: C[M,N] = A[M,K](bf16) @ W[N,K]^T + bias ----------------
// WB==true : W is bf16, staged via global_load_lds (m97 structure)
// WB==false: W is fp32, converted in-kernel (fallback when ws too small)
template <bool WB, bool BF16OUT, bool GELU, bool BIAS>
__global__ __launch_bounds__(256) void k_gemm(const unsigned short* __restrict__ A,
                                              const void* __restrict__ Wv,
                                              const float* __restrict__ bias,
                                              void* __restrict__ Cptr,
                                              int M, int N, int K) {
    __shared__ __align__(16) unsigned short sA[128 * 32];
    __shared__ __align__(16) unsigned short sW[128 * 32];
    int m0 = blockIdx.y * 128, n0 = blockIdx.x * 128;
    int tid = threadIdx.x, lane = tid & 63, wave = tid >> 6;
    int wm = (wave >> 1) * 64, wn = (wave & 1) * 64;
    int lrow = lane & 15, lq = lane >> 4;
    f32x4 acc[4][4] = {};
    int nk = K >> 5;
    const unsigned short* Wb = (const unsigned short*)Wv;
    const float* Wf = (const float*)Wv;
    for (int kt = 0; kt < nk; ++kt) {
        int k0 = kt << 5;
        // stage A (bf16 128x32 = 8KB) direct to LDS, 16B/lane
        #pragma unroll
        for (int i = 0; i < 2; ++i) {
            int c = tid + i * 256;
            int row = c >> 2, seg = c & 3;
            __builtin_amdgcn_global_load_lds(
                (const __attribute__((address_space(1))) void*)(A + (size_t)(m0 + row) * K + k0 + seg * 8),
                (__attribute__((address_space(3))) void*)(sA + (wave * 64 + i * 256) * 8),
                16, 0, 0);
        }
        if constexpr (WB) {
            // stage W (bf16 128x32) direct to LDS
            #pragma unroll
            for (int i = 0; i < 2; ++i) {
                int c = tid + i * 256;
                int row = c >> 2, seg = c & 3;
                __builtin_amdgcn_global_load_lds(
                    (const __attribute__((address_space(1))) void*)(Wb + (size_t)(n0 + row) * K + k0 + seg * 8),
                    (__attribute__((address_space(3))) void*)(sW + (wave * 64 + i * 256) * 8),
                    16, 0, 0);
            }
        } else {
            // stage W (fp32 -> bf16 convert, 128x32)
            #pragma unroll
            for (int j = 0; j < 4; ++j) {
                int c = tid + j * 256;
                int row = c >> 3, seg = c & 7;
                float4 v = *(const float4*)(Wf + (size_t)(n0 + row) * K + k0 + seg * 4);
                unsigned short h0 = f2bf(v.x), h1 = f2bf(v.y), h2 = f2bf(v.z), h3 = f2bf(v.w);
                uint2 pq; pq.x = h0 | ((unsigned)h1 << 16); pq.y = h2 | ((unsigned)h3 << 16);
                *(uint2*)&sW[row * 32 + seg * 4] = pq;
            }
        }
        __syncthreads();
        bf16x8 af[4], bfr[4];
        #pragma unroll
        for (int i = 0; i < 4; ++i) af[i] = *(const bf16x8*)&sA[(wm + i * 16 + lrow) * 32 + lq * 8];
        #pragma unroll
        for (int j = 0; j < 4; ++j) bfr[j] = *(const bf16x8*)&sW[(wn + j * 16 + lrow) * 32 + lq * 8];
        #pragma unroll
        for (int i = 0; i < 4; ++i)
            #pragma unroll
            for (int j = 0; j < 4; ++j)
                acc[i][j] = __builtin_amdgcn_mfma_f32_16x16x32_bf16(af[i], bfr[j], acc[i][j], 0, 0, 0);
        __syncthreads();
    }
    #pragma unroll
    for (int i = 0; i < 4; ++i) {
        #pragma unroll
        for (int j = 0; j < 4; ++j) {
            int col = n0 + wn + j * 16 + lrow;
            float bb = BIAS ? bias[col] : 0.0f;
            #pragma unroll
            for (int r = 0; r < 4; ++r) {
                int row = m0 + wm + i * 16 + lq * 4 + r;
                float v = acc[i][j][r] + bb;
                if (GELU) v = gelu_f(v);
                if (BF16OUT)
                    ((unsigned short*)Cptr)[(size_t)row * N + col] = f2bf(v);
                else
                    ((float*)Cptr)[(size_t)row * N + col] = v;
            }
        }
    }
}

// ---------------- rope + qkv split (bf16 qkv -> Q,K,V head-major) ----------------
__global__ __launch_bounds__(256) void k_rope(const unsigned short* __restrict__ qkv,
                                              unsigned short* __restrict__ Qb,
                                              unsigned short* __restrict__ Kb,
                                              unsigned short* __restrict__ Vb) {
    int s = blockIdx.x;
    const unsigned short* row = qkv + (size_t)s * (3 * H_);
    for (int e = threadIdx.x; e < H_; e += 256) {
        int h = e >> 7, d = e & 127;
        int base = h * 384;
        float q = bf2f(row[base + d]);
        float k = bf2f(row[base + 128 + d]);
        float v = bf2f(row[base + 256 + d]);
        if (d < ROT_) {
            int i = d & 15;
            float invf = powf(10000.0f, -(float)i * (1.0f / 16.0f));
            float ang = (float)s * invf;
            float c, sn;
            sincosf(ang, &sn, &c);
            float qo = (d < 16) ? -bf2f(row[base + d + 16]) : bf2f(row[base + d - 16]);
            float ko = (d < 16) ? -bf2f(row[base + 128 + d + 16]) : bf2f(row[base + 128 + d - 16]);
            q = q * c + qo * sn;
            k = k * c + ko * sn;
        }
        size_t o = ((size_t)h * S_ + s) * HD_ + d;
        Qb[o] = f2bf(q);
        Kb[o] = f2bf(k);
        Vb[o] = f2bf(v);
    }
}

// ---------------- flash attention (64 q-rows x 64 kv per tile) ----------------
#define ATP 24
__global__ __launch_bounds__(256) void k_attn(const unsigned short* __restrict__ Q,
                                              const unsigned short* __restrict__ K,
                                              const unsigned short* __restrict__ V,
                                              unsigned short* __restrict__ ctx) {
    __shared__ __align__(16) unsigned short sQ[64][128 + ATP];
    __shared__ __align__(16) unsigned short sK[64][128 + ATP];
    __shared__ __align__(16) unsigned short sVt[128][64 + ATP];
    __shared__ __align__(16) unsigned short sP[64][64 + ATP];
    int qt = blockIdx.x, h = blockIdx.y;
    int q0 = qt * 64;
    int tid = threadIdx.x, lane = tid & 63, w = tid >> 6;
    int lrow = lane & 15, lq = lane >> 4;
    const unsigned short* Qh = Q + (size_t)h * S_ * HD_;
    const unsigned short* Kh = K + (size_t)h * S_ * HD_;
    const unsigned short* Vh = V + (size_t)h * S_ * HD_;
    for (int c = tid; c < 64 * 16; c += 256) {
        int row = c >> 4, cc = c & 15;
        *(uint4*)&sQ[row][cc * 8] = *(const uint4*)(Qh + (size_t)(q0 + row) * HD_ + cc * 8);
    }
    __syncthreads();
    bf16x8 qf[4];
    #pragma unroll
    for (int kk = 0; kk < 4; ++kk) qf[kk] = *(const bf16x8*)&sQ[w * 16 + lrow][kk * 32 + lq * 8];
    f32x4 o[8] = {};
    float m_i[4], l_i[4];
    #pragma unroll
    for (int r = 0; r < 4; ++r) { m_i[r] = -1e30f; l_i[r] = 0.0f; }
    const float scale = 0.08838834764831845f;  // 1/sqrt(128)
    int ntiles = qt + 1;
    for (int t = 0; t < ntiles; ++t) {
        int k0 = t * 64;
        for (int c = tid; c < 64 * 16; c += 256) {
            int row = c >> 4, cc = c & 15;
            *(uint4*)&sK[row][cc * 8] = *(const uint4*)(Kh + (size_t)(k0 + row) * HD_ + cc * 8);
        }
        for (int c = tid; c < 64 * 32; c += 256) {
            int kv = c >> 5, d0 = (c & 31) * 4;
            ushort4 vv = *(const ushort4*)(Vh + (size_t)(k0 + kv) * HD_ + d0);
            sVt[d0 + 0][kv] = vv.x;
            sVt[d0 + 1][kv] = vv.y;
            sVt[d0 + 2][kv] = vv.z;
            sVt[d0 + 3][kv] = vv.w;
        }
        __syncthreads();
        f32x4 sc[4] = {};
        #pragma unroll
        for (int kk = 0; kk < 4; ++kk) {
            #pragma unroll
            for (int j = 0; j < 4; ++j) {
                bf16x8 kfr = *(const bf16x8*)&sK[j * 16 + lrow][kk * 32 + lq * 8];
                sc[j] = __builtin_amdgcn_mfma_f32_16x16x32_bf16(qf[kk], kfr, sc[j], 0, 0, 0);
            }
        }
        // scale + causal mask + row max
        float rmax[4];
        #pragma unroll
        for (int r = 0; r < 4; ++r) {
            int qg = q0 + w * 16 + lq * 4 + r;
            float mx = -1e30f;
            #pragma unroll
            for (int j = 0; j < 4; ++j) {
                int kg = k0 + j * 16 + lrow;
                float vv = sc[j][r] * scale;
                if (kg > qg) vv = -1e30f;
                sc[j][r] = vv;
                mx = fmaxf(mx, vv);
            }
            rmax[r] = mx;
        }
        #pragma unroll
        for (int off = 1; off < 16; off <<= 1)
            #pragma unroll
            for (int r = 0; r < 4; ++r) rmax[r] = fmaxf(rmax[r], __shfl_xor(rmax[r], off, 16));
        float alpha[4];
        #pragma unroll
        for (int r = 0; r < 4; ++r) {
            float mn = fmaxf(m_i[r], rmax[r]);
            alpha[r] = __expf(m_i[r] - mn);
            m_i[r] = mn;
        }
        float rsum[4] = {0.f, 0.f, 0.f, 0.f};
        #pragma unroll
        for (int j = 0; j < 4; ++j)
            #pragma unroll
            for (int r = 0; r < 4; ++r) {
                float p = __expf(sc[j][r] - m_i[r]);
                sc[j][r] = p;
                rsum[r] += p;
            }
        #pragma unroll
        for (int off = 1; off < 16; off <<= 1)
            #pragma unroll
            for (int r = 0; r < 4; ++r) rsum[r] += __shfl_xor(rsum[r], off, 16);
        #pragma unroll
        for (int r = 0; r < 4; ++r) l_i[r] = l_i[r] * alpha[r] + rsum[r];
        // write P (bf16) to LDS in C-layout
        #pragma unroll
        for (int j = 0; j < 4; ++j)
            #pragma unroll
            for (int r = 0; r < 4; ++r)
                sP[w * 16 + lq * 4 + r][j * 16 + lrow] = f2bf(sc[j][r]);
        // rescale O
        #pragma unroll
        for (int n = 0; n < 8; ++n)
            #pragma unroll
            for (int r = 0; r < 4; ++r) o[n][r] *= alpha[r];
        __syncthreads();
        // PV: O += P @ V
        bf16x8 pa[2];
        #pragma unroll
        for (int kk = 0; kk < 2; ++kk) pa[kk] = *(const bf16x8*)&sP[w * 16 + lrow][kk * 32 + lq * 8];
        #pragma unroll
        for (int n = 0; n < 8; ++n) {
            #pragma unroll
            for (int kk = 0; kk < 2; ++kk) {
                bf16x8 vf = *(const bf16x8*)&sVt[n * 16 + lrow][kk * 32 + lq * 8];
                o[n] = __builtin_amdgcn_mfma_f32_16x16x32_bf16(pa[kk], vf, o[n], 0, 0, 0);
            }
        }
        __syncthreads();
    }
    #pragma unroll
    for (int n = 0; n < 8; ++n)
        #pragma unroll
        for (int r = 0; r < 4; ++r) {
            int row = q0 + w * 16 + lq * 4 + r;
            int d = n * 16 + lrow;
            ctx[(size_t)row * H_ + h * HD_ + d] = f2bf(o[n][r] / l_i[r]);
        }
}

// ---------------- residual: h += attn + mlp ----------------
__global__ __launch_bounds__(256) void k_resid(float* __restrict__ h,
                                               const float* __restrict__ a,
                                               const float* __restrict__ m, int n4) {
    int i = blockIdx.x * 256 + threadIdx.x;
    if (i < n4) {
        float4 hv = ((float4*)h)[i];
        float4 av = ((const float4*)a)[i];
        float4 mv = ((const float4*)m)[i];
        hv.x += av.x + mv.x;
        hv.y += av.y + mv.y;
        hv.z += av.z + mv.z;
        hv.w += av.w + mv.w;
        ((float4*)h)[i] = hv;
    }
}

extern "C" void kernel_launch(void* const* d_in, const int* in_sizes, int n_in,
                              void* d_out, int out_size, void* d_ws, size_t ws_size,
                              hipStream_t stream) {
    const int* tokens = (const int*)d_in[0];
    const float* embed = (const float*)d_in[1];
    const float* ln1_g = (const float*)d_in[2];
    const float* ln1_b = (const float*)d_in[3];
    const float* ln2_g = (const float*)d_in[4];
    const float* ln2_b = (const float*)d_in[5];
    const float* qkv_w = (const float*)d_in[6];
    const float* qkv_b = (const float*)d_in[7];
    const float* aow = (const float*)d_in[8];
    const float* aob = (const float*)d_in[9];
    const float* fc1w = (const float*)d_in[10];
    const float* fc1b = (const float*)d_in[11];
    const float* fc2w = (const float*)d_in[12];
    const float* fc2b = (const float*)d_in[13];
    const float* lnfg = (const float*)d_in[14];
    const float* lnfb = (const float*)d_in[15];
    const float* logw = (const float*)d_in[16];

    char* p = (char*)d_ws;
    auto alloc = [&](size_t bytes) {
        char* r = p;
        p += (bytes + 255) & ~(size_t)255;
        return r;
    };
    float* h = (float*)alloc((size_t)S_ * H_ * 4);
    unsigned short* xb = (unsigned short*)alloc((size_t)S_ * H_ * 2);
    unsigned short* qkv = (unsigned short*)alloc((size_t)S_ * 3 * H_ * 2);
    unsigned short* Qb = (unsigned short*)alloc((size_t)NH_ * S_ * HD_ * 2);
    unsigned short* Kb = (unsigned short*)alloc((size_t)NH_ * S_ * HD_ * 2);
    unsigned short* Vb = (unsigned short*)alloc((size_t)NH_ * S_ * HD_ * 2);
    unsigned short* ctx = (unsigned short*)alloc((size_t)S_ * H_ * 2);
    float* attn = (float*)alloc((size_t)S_ * H_ * 4);
    unsigned short* f1 = (unsigned short*)alloc((size_t)S_ * 4 * H_ * 2);
    float* mlp = (float*)alloc((size_t)S_ * H_ * 4);
    // bf16 weight copies (pre-converted once per launch)
    unsigned short* wqkv = (unsigned short*)alloc((size_t)L_ * 3 * H_ * H_ * 2);
    unsigned short* waow = (unsigned short*)alloc((size_t)L_ * H_ * H_ * 2);
    unsigned short* wfc1 = (unsigned short*)alloc((size_t)L_ * 4 * H_ * H_ * 2);
    unsigned short* wfc2 = (unsigned short*)alloc((size_t)L_ * H_ * 4 * H_ * 2);
    unsigned short* wlog = (unsigned short*)alloc((size_t)V_ * H_ * 2);
    bool pre = ((size_t)(p - (char*)d_ws) <= ws_size);

    k_embed<<<S_, 256, 0, stream>>>(tokens, embed, h);
    if (pre) {
        k_cvt<<<2048, 256, 0, stream>>>(qkv_w, wqkv, L_ * 3 * H_ * H_ / 4);
        k_cvt<<<2048, 256, 0, stream>>>(aow, waow, L_ * H_ * H_ / 4);
        k_cvt<<<2048, 256, 0, stream>>>(fc1w, wfc1, L_ * 4 * H_ * H_ / 4);
        k_cvt<<<2048, 256, 0, stream>>>(fc2w, wfc2, L_ * H_ * 4 * H_ / 4);
        k_cvt<<<2048, 256, 0, stream>>>(logw, wlog, V_ * H_ / 4);
    }
    for (int l = 0; l < L_; ++l) {
        k_ln<<<S_, 256, 0, stream>>>(h, ln1_g + l * H_, ln1_b + l * H_, xb);
        if (pre)
            k_gemm<true, true, false, true><<<dim3(3 * H_ / 128, S_ / 128), 256, 0, stream>>>(
                xb, wqkv + (size_t)l * 3 * H_ * H_, qkv_b + l * 3 * H_, qkv, S_, 3 * H_, H_);
        else
            k_gemm<false, true, false, true><<<dim3(3 * H_ / 128, S_ / 128), 256, 0, stream>>>(
                xb, qkv_w + (size_t)l * 3 * H_ * H_, qkv_b + l * 3 * H_, qkv, S_, 3 * H_, H_);
        k_rope<<<S_, 256, 0, stream>>>(qkv, Qb, Kb, Vb);
        k_attn<<<dim3(S_ / 64, NH_), 256, 0, stream>>>(Qb, Kb, Vb, ctx);
        if (pre)
            k_gemm<true, false, false, true><<<dim3(H_ / 128, S_ / 128), 256, 0, stream>>>(
                ctx, waow + (size_t)l * H_ * H_, aob + l * H_, attn, S_, H_, H_);
        else
            k_gemm<false, false, false, true><<<dim3(H_ / 128, S_ / 128), 256, 0, stream>>>(
                ctx, aow + (size_t)l * H_ * H_, aob + l * H_, attn, S_, H_, H_);
        k_ln<<<S_, 256, 0, stream>>>(h, ln2_g + l * H_, ln2_b + l * H_, xb);
        if (pre)
            k_gemm<true, true, true, true><<<dim3(4 * H_ / 128, S_ / 128), 256, 0, stream>>>(
                xb, wfc1 + (size_t)l * 4 * H_ * H_, fc1b + l * 4 * H_, f1, S_, 4 * H_, H_);
        else
            k_gemm<false, true, true, true><<<dim3(4 * H_ / 128, S_ / 128), 256, 0, stream>>>(
                xb, fc1w + (size_t)l * 4 * H_ * H_, fc1b + l * 4 * H_, f1, S_, 4 * H_, H_);
        if (pre)
            k_gemm<true, false, false, true><<<dim3(H_ / 128, S_ / 128), 256, 0, stream>>>(
                f1, wfc2 + (size_t)l * H_ * 4 * H_, fc2b + l * H_, mlp, S_, H_, 4 * H_);
        else
            k_gemm<false, false, false, true><<<dim3(H_ / 128, S_ / 128), 256, 0, stream>>>(
                f1, fc2w + (size_t)l * H_ * 4 * H_, fc2b + l * H_, mlp, S_, H_, 4 * H_);
        k_resid<<<(S_ * H_ / 4 + 255) / 256, 256, 0, stream>>>(h, attn, mlp, S_ * H_ / 4);
    }
    k_ln<<<S_, 256, 0, stream>>>(h, lnfg, lnfb, xb);
    if (pre)
        k_gemm<true, false, false, false><<<dim3(V_ / 128, S_ / 128), 256, 0, stream>>>(
            xb, wlog, nullptr, (float*)d_out, S_, V_, H_);
    else
        k_gemm<false, false, false, false><<<dim3(V_ / 128, S_ / 128), 256, 0, stream>>>(
            xb, logw, nullptr, (float*)d_out, S_, V_, H_);
}